// Round 1
// baseline (259.783 us; speedup 1.0000x reference)
//
#include <hip/hip_runtime.h>
#include <hip/hip_bf16.h>

// TreeLoss: hierarchical softmax-style loss over a fixed 2-level tree.
// States: 1 empty + 24 coarse-only + 1000 (coarse,fine) pairs.
// z = 1 + sum_c e_c + sum_f e_{f%24} * e_{24+f}
// marginal(label<24=c)  = e_c * (1 + sum_{f≡c(24)} e_{24+f})
// marginal(label>=24)   = e_{(label-24)%24} * e_label
// out = mean(log z - log marginal)

constexpr int N_COARSE = 24;
constexpr int TOTAL = 1024;      // columns per row
constexpr int BATCH = 32768;
constexpr int WAVES_PER_BLOCK = 4;   // 256 threads

__global__ __launch_bounds__(256) void treeloss_kernel(
    const float* __restrict__ fs, const int* __restrict__ labels,
    float* __restrict__ out) {
  const int wave = threadIdx.x >> 6;
  const int lane = threadIdx.x & 63;
  const int b = blockIdx.x * WAVES_PER_BLOCK + wave;  // BATCH % 4 == 0, no guard

  __shared__ float sc[WAVES_PER_BLOCK][N_COARSE];
  __shared__ float blocksum[WAVES_PER_BLOCK];

  const float* __restrict__ row = fs + (size_t)b * TOTAL;
  const int label = labels[b];

  // Pass A: coarse exponentials into LDS (per-wave region).
  if (lane < N_COARSE) sc[wave][lane] = __expf(row[lane]);
  __syncthreads();

  // Pass B: stream the full row, 16 columns/lane as 4x float4.
  float zp = 0.0f;   // partial of (z - 1)
  float sp = 0.0f;   // partial of marginal
#pragma unroll
  for (int j = 0; j < 4; ++j) {
    const int n0 = j * 256 + lane * 4;
    const float4 v = *reinterpret_cast<const float4*>(row + n0);
    const float vv[4] = {v.x, v.y, v.z, v.w};
#pragma unroll
    for (int k = 0; k < 4; ++k) {
      const int n = n0 + k;
      const float en = __expf(vv[k]);
      if (n < N_COARSE) {
        // coarse-only state
        zp += en;
        if (n == label) sp += en;
      } else {
        // pair state (c, n) with c = (n-24) % 24 == n % 24
        const int c = n % N_COARSE;
        const float t = sc[wave][c] * en;
        zp += t;
        if (n == label || c == label) sp += t;
      }
    }
  }

  // Wave-wide butterfly reduce (64 lanes).
#pragma unroll
  for (int off = 32; off > 0; off >>= 1) {
    zp += __shfl_down(zp, off);
    sp += __shfl_down(sp, off);
  }

  if (lane == 0) {
    const float z = 1.0f + zp;
    blocksum[wave] = logf(z) - logf(sp);
  }
  __syncthreads();

  if (threadIdx.x == 0) {
    float s = 0.0f;
#pragma unroll
    for (int w = 0; w < WAVES_PER_BLOCK; ++w) s += blocksum[w];
    atomicAdd(out, s * (1.0f / (float)BATCH));
  }
}

extern "C" void kernel_launch(void* const* d_in, const int* in_sizes, int n_in,
                              void* d_out, int out_size, void* d_ws, size_t ws_size,
                              hipStream_t stream) {
  const float* fs = (const float*)d_in[0];
  const int* labels = (const int*)d_in[1];
  // d_in[2] (stateSpace) is deterministic structure; hardcoded in the kernel.
  float* out = (float*)d_out;

  hipMemsetAsync(out, 0, sizeof(float), stream);  // d_out is poisoned 0xAA pre-launch
  const int grid = BATCH / WAVES_PER_BLOCK;       // 8192
  treeloss_kernel<<<grid, 256, 0, stream>>>(fs, labels, out);
}

// Round 2
// 191.552 us; speedup vs baseline: 1.3562x; 1.3562x over previous
//
#include <hip/hip_runtime.h>
#include <hip/hip_bf16.h>

// TreeLoss: hierarchical softmax-style loss over a fixed 2-level tree.
// States: 1 empty + 24 coarse-only + 1000 (coarse,fine) pairs.
// z = 1 + sum_c e_c + sum_f e_{f%24} * e_{24+f}
// marginal(label<24=c)  = e_c * (1 + sum_{f≡c(24)} e_{24+f})
// marginal(label>=24)   = e_{(label-24)%24} * e_label
// out = mean(log z - log marginal)
//
// R1: replaced 8192 same-address atomicAdds (serialize at ~14 ns each ≈ the
// entire 115 µs of R0 — confirmed by a zero-HBM dispatch at identical dur)
// with a two-stage reduction through d_ws.

constexpr int N_COARSE = 24;
constexpr int TOTAL = 1024;      // columns per row
constexpr int BATCH = 32768;
constexpr int WAVES_PER_BLOCK = 4;   // 256 threads
constexpr int GRID1 = BATCH / WAVES_PER_BLOCK;  // 8192 blocks, one partial each

__global__ __launch_bounds__(256) void treeloss_partial(
    const float* __restrict__ fs, const int* __restrict__ labels,
    float* __restrict__ partials) {
  const int wave = threadIdx.x >> 6;
  const int lane = threadIdx.x & 63;
  const int b = blockIdx.x * WAVES_PER_BLOCK + wave;  // BATCH % 4 == 0, no guard

  __shared__ float sc[WAVES_PER_BLOCK][N_COARSE];
  __shared__ float blocksum[WAVES_PER_BLOCK];

  const float* __restrict__ row = fs + (size_t)b * TOTAL;
  const int label = labels[b];

  // Pass A: coarse exponentials into LDS (per-wave region).
  if (lane < N_COARSE) sc[wave][lane] = __expf(row[lane]);
  __syncthreads();

  // Pass B: stream the full row, 16 columns/lane as 4x float4.
  float zp = 0.0f;   // partial of (z - 1)
  float sp = 0.0f;   // partial of marginal
#pragma unroll
  for (int j = 0; j < 4; ++j) {
    const int n0 = j * 256 + lane * 4;
    const float4 v = *reinterpret_cast<const float4*>(row + n0);
    const float vv[4] = {v.x, v.y, v.z, v.w};
#pragma unroll
    for (int k = 0; k < 4; ++k) {
      const int n = n0 + k;
      const float en = __expf(vv[k]);
      if (j == 0 && n < N_COARSE) {
        // coarse-only state
        zp += en;
        if (n == label) sp += en;
      } else {
        // pair state (c, n) with c = (n-24) % 24 == n % 24
        const int c = n % N_COARSE;
        const float t = sc[wave][c] * en;
        zp += t;
        if (n == label || c == label) sp += t;
      }
    }
  }

  // Wave-wide butterfly reduce (64 lanes).
#pragma unroll
  for (int off = 32; off > 0; off >>= 1) {
    zp += __shfl_down(zp, off);
    sp += __shfl_down(sp, off);
  }

  if (lane == 0) {
    const float z = 1.0f + zp;
    blocksum[wave] = logf(z) - logf(sp);
  }
  __syncthreads();

  if (threadIdx.x == 0) {
    partials[blockIdx.x] = blocksum[0] + blocksum[1] + blocksum[2] + blocksum[3];
  }
}

__global__ __launch_bounds__(256) void treeloss_reduce(
    const float* __restrict__ partials, float* __restrict__ out) {
  const int lane = threadIdx.x & 63;
  const int wave = threadIdx.x >> 6;
  float s = 0.0f;
#pragma unroll
  for (int i = 0; i < GRID1 / 256; ++i)  // 32 coalesced loads/thread
    s += partials[threadIdx.x + i * 256];
#pragma unroll
  for (int off = 32; off > 0; off >>= 1) s += __shfl_down(s, off);
  __shared__ float ps[WAVES_PER_BLOCK];
  if (lane == 0) ps[wave] = s;
  __syncthreads();
  if (threadIdx.x == 0)
    out[0] = (ps[0] + ps[1] + ps[2] + ps[3]) * (1.0f / (float)BATCH);
}

extern "C" void kernel_launch(void* const* d_in, const int* in_sizes, int n_in,
                              void* d_out, int out_size, void* d_ws, size_t ws_size,
                              hipStream_t stream) {
  const float* fs = (const float*)d_in[0];
  const int* labels = (const int*)d_in[1];
  // d_in[2] (stateSpace) is deterministic structure; hardcoded in the kernel.
  float* out = (float*)d_out;
  float* partials = (float*)d_ws;  // 8192 floats = 32 KiB scratch

  treeloss_partial<<<GRID1, 256, 0, stream>>>(fs, labels, partials);
  treeloss_reduce<<<1, 256, 0, stream>>>(partials, out);
}

// Round 3
// 189.585 us; speedup vs baseline: 1.3703x; 1.0104x over previous
//
#include <hip/hip_runtime.h>
#include <hip/hip_bf16.h>

// TreeLoss: hierarchical softmax-style loss over a fixed 2-level tree.
// States: 1 empty + 24 coarse-only + 1000 (coarse,fine) pairs.
// z = 1 + sum_c e_c + sum_{n>=24} e_{n%24} * e_n
// marginal(label<24=c)  = e_c * (1 + sum_{n≡c (24), n>=24} e_n)
// marginal(label>=24)   = e_{label%24} * e_label
// out = mean(log z - log marginal)
//
// R1: two-stage reduction replaced 8192 same-address atomics (−68 us).
// R2: main loop stripped to mul+exp+ds_read(imm offset)+fma:
//     - label logic hoisted out of the loop (<=42-lane predicated gather)
//     - per-element %24 killed via 48-entry replicated LDS coarse table
//       (index = cbase + compile-time K, max 39 < 48, conflict-free)
//     - all 4 float4 row loads issued up-front for ILP
// Note: ~120 us of the reported dur is harness restore/poison (512 MiB ws
// fill at 78 us tops the profile); only ~50 us was ours entering this round.

constexpr int N_COARSE = 24;
constexpr int TOTAL = 1024;      // columns per row
constexpr int BATCH = 32768;
constexpr int WAVES_PER_BLOCK = 4;   // 256 threads
constexpr int GRID1 = BATCH / WAVES_PER_BLOCK;  // 8192 blocks, one partial each

__global__ __launch_bounds__(256) void treeloss_partial(
    const float* __restrict__ fs, const int* __restrict__ labels,
    float* __restrict__ partials) {
  const int wave = threadIdx.x >> 6;
  const int lane = threadIdx.x & 63;
  const int b = blockIdx.x * WAVES_PER_BLOCK + wave;  // BATCH % 4 == 0

  __shared__ float sc48[WAVES_PER_BLOCK][48];  // coarse exps, replicated x2
  __shared__ float blocksum[WAVES_PER_BLOCK];

  const float* __restrict__ row = fs + (size_t)b * TOTAL;
  const float4* __restrict__ row4 = reinterpret_cast<const float4*>(row);
  const int label = labels[b];

  // Issue the whole row up-front: 4x float4 per lane, fully coalesced.
  const float4 v0 = row4[lane];
  const float4 v1 = row4[lane + 64];
  const float4 v2 = row4[lane + 128];
  const float4 v3 = row4[lane + 192];

  // Coarse exp table, replicated so indices never need a mod/wrap.
  if (lane < N_COARSE) {
    const float e = __expf(row[lane]);
    sc48[wave][lane] = e;
    sc48[wave][lane + N_COARSE] = e;
  }
  __syncthreads();

  const int cbase = (lane * 4) % N_COARSE;  // one-time magic-mul, in {0,4,..,20}
  float zp = 0.0f;  // partial of (z - 1)

  // j = 0: columns n = 4*lane + k; n < 24 are coarse-only states.
  {
    const float vv[4] = {v0.x, v0.y, v0.z, v0.w};
#pragma unroll
    for (int k = 0; k < 4; ++k) {
      const int n = lane * 4 + k;
      const float en = __expf(vv[k]);
      if (n < N_COARSE) zp += en;                       // lanes 0..5 only
      else zp += sc48[wave][cbase + k] * en;            // c = cbase+k <= 23
    }
  }
  // j = 1..3: K = (j*256) % 24 is a compile-time constant (16, 8, 0).
  {
    const float vv[4] = {v1.x, v1.y, v1.z, v1.w};
#pragma unroll
    for (int k = 0; k < 4; ++k)
      zp += sc48[wave][cbase + 16 + k] * __expf(vv[k]);  // idx <= 39 < 48
  }
  {
    const float vv[4] = {v2.x, v2.y, v2.z, v2.w};
#pragma unroll
    for (int k = 0; k < 4; ++k)
      zp += sc48[wave][cbase + 8 + k] * __expf(vv[k]);
  }
  {
    const float vv[4] = {v3.x, v3.y, v3.z, v3.w};
#pragma unroll
    for (int k = 0; k < 4; ++k)
      zp += sc48[wave][cbase + k] * __expf(vv[k]);
  }

  // Label gather (out of the hot loop). For label<24: fine nodes ≡ label mod 24
  // are label+24*(lane+1), at most 42 of them; loads are L1/L2-hot.
  float g = 0.0f;
  if (label < N_COARSE) {
    const int idx = label + N_COARSE * (lane + 1);
    if (idx < TOTAL) g = __expf(row[idx]);
  }

  // Wave-wide butterfly reduce (64 lanes).
#pragma unroll
  for (int off = 32; off > 0; off >>= 1) {
    zp += __shfl_down(zp, off);
    g += __shfl_down(g, off);
  }

  if (lane == 0) {
    float m;
    if (label < N_COARSE) m = sc48[wave][label] * (1.0f + g);
    else m = sc48[wave][label % N_COARSE] * __expf(row[label]);
    blocksum[wave] = __logf(1.0f + zp) - __logf(m);
  }
  __syncthreads();

  if (threadIdx.x == 0) {
    partials[blockIdx.x] = blocksum[0] + blocksum[1] + blocksum[2] + blocksum[3];
  }
}

__global__ __launch_bounds__(1024) void treeloss_reduce(
    const float* __restrict__ partials, float* __restrict__ out) {
  const int tid = threadIdx.x;
  const int lane = tid & 63;
  const int wave = tid >> 6;
  const float4* __restrict__ p4 = reinterpret_cast<const float4*>(partials);
  const float4 a = p4[tid];           // 8192 floats = 2048 float4
  const float4 c = p4[tid + 1024];
  float s = (a.x + a.y + a.z + a.w) + (c.x + c.y + c.z + c.w);
#pragma unroll
  for (int off = 32; off > 0; off >>= 1) s += __shfl_down(s, off);
  __shared__ float ps[16];
  if (lane == 0) ps[wave] = s;
  __syncthreads();
  if (tid == 0) {
    float t = 0.0f;
#pragma unroll
    for (int w = 0; w < 16; ++w) t += ps[w];
    out[0] = t * (1.0f / (float)BATCH);
  }
}

extern "C" void kernel_launch(void* const* d_in, const int* in_sizes, int n_in,
                              void* d_out, int out_size, void* d_ws, size_t ws_size,
                              hipStream_t stream) {
  const float* fs = (const float*)d_in[0];
  const int* labels = (const int*)d_in[1];
  // d_in[2] (stateSpace) is deterministic structure; hardcoded in the kernel.
  float* out = (float*)d_out;
  float* partials = (float*)d_ws;  // 8192 floats = 32 KiB scratch

  treeloss_partial<<<GRID1, 256, 0, stream>>>(fs, labels, partials);
  treeloss_reduce<<<1, 1024, 0, stream>>>(partials, out);
}